// Round 11
// baseline (816.587 us; speedup 1.0000x reference)
//
#include <hip/hip_runtime.h>

#define N_NODES 50000
#define N_EDGES 800000

typedef __attribute__((ext_vector_type(8))) short short8;
typedef __attribute__((ext_vector_type(4))) float f32x4;

// float -> bf16 (round-to-nearest-even), bit pattern in a short.
__device__ __forceinline__ short bf16_rne(float f) {
  unsigned u = __float_as_uint(f);
  unsigned r = (u + 0x7FFFu + ((u >> 16) & 1u)) >> 16;
  return (short)r;
}

// ---------------------------------------------------------------------------
// hist_prep: fused dst-histogram + frag-linear bf16 weight table build.
// Blocks [0, 3125): histogram of dst. Blocks [3125, 3285): prep_w.
// Wbf[((kt*20+ct)*64 + L)*8 + j] = W[k = kt*32 + (L>>4)*8 + j][oc = ct*16 + (L&15)]
// oc map: 0-63 = Wa_d | 64-127 = W_e | 128-191 = Wa_s | 192-255 = Wt_s | 256-319 = Wt_d
// ---------------------------------------------------------------------------
__global__ __launch_bounds__(256) void hist_prep(
    const int* __restrict__ dst, unsigned* __restrict__ hist,
    const float* __restrict__ W_a, const float* __restrict__ W_T,
    const float* __restrict__ W_e, unsigned short* __restrict__ Wbf) {
  const int bid = blockIdx.x;
  if (bid < N_EDGES / 256) {
    int e = bid * 256 + threadIdx.x;
    atomicAdd(&hist[dst[e]], 1u);
  } else {
    int t = (bid - N_EDGES / 256) * 256 + threadIdx.x;
    if (t >= 4 * 20 * 64 * 8) return;
    int kt = t / 10240, rdm = t % 10240;
    int ct = rdm >> 9, L = (rdm >> 3) & 63, j = rdm & 7;
    int k = kt * 32 + (L >> 4) * 8 + j;
    int oc = ct * 16 + (L & 15);
    float v;
    if (oc < 64)       v = W_a[k * 64 + oc];
    else if (oc < 128) v = W_e[k * 64 + (oc - 64)];
    else if (oc < 192) v = W_a[(192 + k) * 64 + (oc - 128)];
    else if (oc < 256) v = W_T[(192 + k) * 64 + (oc - 192)];
    else               v = W_T[k * 64 + (oc - 256)];
    Wbf[t] = (unsigned short)bf16_rne(v);
  }
}

// ---------------------------------------------------------------------------
// scan_cursor: one block, 1024 threads, 2-level exclusive scan of hist.
// ---------------------------------------------------------------------------
__global__ __launch_bounds__(1024) void scan_cursor(
    const unsigned* __restrict__ hist, unsigned* __restrict__ cursor) {
  __shared__ unsigned sSums[16];
  const int tid = threadIdx.x;
  const int lane = tid & 63;
  const int w = tid >> 6;
  const int CH = (N_NODES + 1023) / 1024;  // 49
  const int begin = tid * CH;
  const int end = (begin + CH < N_NODES) ? begin + CH : N_NODES;

  unsigned local = 0;
  for (int i = begin; i < end; ++i) local += hist[i];

  unsigned sum = local;
  #pragma unroll
  for (int off = 1; off < 64; off <<= 1) {
    unsigned t = __shfl_up(sum, off, 64);
    if (lane >= off) sum += t;
  }
  if (lane == 63) sSums[w] = sum;
  __syncthreads();
  if (w == 0) {
    unsigned v = (lane < 16) ? sSums[lane] : 0u;
    unsigned s2 = v;
    #pragma unroll
    for (int off = 1; off < 16; off <<= 1) {
      unsigned t = __shfl_up(s2, off, 64);
      if (lane >= off) s2 += t;
    }
    if (lane < 16) sSums[lane] = s2 - v;
  }
  __syncthreads();

  unsigned run = sSums[w] + (sum - local);
  for (int i = begin; i < end; ++i) {
    cursor[i] = run;
    run += hist[i];
  }
}

// ---------------------------------------------------------------------------
// scatter: edge e -> dst-sorted slot; payload int2{src, e} + sdst.
// ---------------------------------------------------------------------------
__global__ __launch_bounds__(256) void scatter_kernel(
    const int* __restrict__ src, const int* __restrict__ dst,
    unsigned* __restrict__ cursor, int2* __restrict__ se,
    int* __restrict__ sdst) {
  int e = blockIdx.x * 256 + threadIdx.x;
  if (e >= N_EDGES) return;
  int d = dst[e];
  unsigned pos = atomicAdd(&cursor[d], 1u);
  se[pos] = make_int2(src[e], e);
  sdst[pos] = d;
}

// ---------------------------------------------------------------------------
// node_proj_mfma: NP = n_feat @ [Wa_d|W_e|Wa_s|Wt_s|Wt_d] via bf16 MFMA.
// Packed gather table: NPs4[n][lane] = uint2{ e | as<<16 , ts | ad<<16 }.
// ---------------------------------------------------------------------------
__global__ __launch_bounds__(256) void node_proj_mfma(
    const float* __restrict__ n_feat, const unsigned short* __restrict__ Wbf,
    uint2* __restrict__ NPs4, float* __restrict__ Ptd) {
  __shared__ short sA[64 * 128];  // 16 KB bf16
  const int tid = threadIdx.x;
  const int lane = tid & 63;
  const int wid = tid >> 6;
  const int n0 = blockIdx.x * 64;

  for (int cid = tid; cid < 64 * 16; cid += 256) {
    int nd = cid >> 4, k8 = cid & 15;
    int nsrc = n0 + nd; if (nsrc >= N_NODES) nsrc = N_NODES - 1;
    const float* p = n_feat + (size_t)nsrc * 128 + k8 * 8;
    float4 v0 = *(const float4*)p;
    float4 v1 = *(const float4*)(p + 4);
    short8 a;
    a[0] = bf16_rne(v0.x); a[1] = bf16_rne(v0.y);
    a[2] = bf16_rne(v0.z); a[3] = bf16_rne(v0.w);
    a[4] = bf16_rne(v1.x); a[5] = bf16_rne(v1.y);
    a[6] = bf16_rne(v1.z); a[7] = bf16_rne(v1.w);
    *(short8*)(&sA[nd * 128 + ((k8 ^ (nd & 7)) << 3)]) = a;
  }
  __syncthreads();

  const int row = lane & 15;
  const int q   = lane >> 4;

  short8 afrag[4];
  #pragma unroll
  for (int kt = 0; kt < 4; ++kt) {
    int nd = wid * 16 + row;
    afrag[kt] = *(const short8*)(&sA[nd * 128 + (((kt * 4 + q) ^ (row & 7)) << 3)]);
  }

  const short8* Wb8 = (const short8*)Wbf;
  f32x4 acc[20];
  #pragma unroll
  for (int ct = 0; ct < 20; ++ct) acc[ct] = (f32x4){0.f, 0.f, 0.f, 0.f};
  #pragma unroll
  for (int ct = 0; ct < 20; ++ct)
    #pragma unroll
    for (int kt = 0; kt < 4; ++kt) {
      short8 b = Wb8[(kt * 20 + ct) * 64 + lane];
      acc[ct] = __builtin_amdgcn_mfma_f32_16x16x32_bf16(afrag[kt], b, acc[ct], 0, 0, 0);
    }

  // D layout: col = i*16 + row, node-row = q*4 + r  [m89-verified]
  #pragma unroll
  for (int i = 0; i < 4; ++i)
    #pragma unroll
    for (int r = 0; r < 4; ++r) {
      int nd = n0 + wid * 16 + q * 4 + r;
      if (nd < N_NODES) {
        unsigned e16  = (unsigned short)bf16_rne(acc[4  + i][r]);
        unsigned as16 = (unsigned short)bf16_rne(acc[8  + i][r]);
        unsigned ts16 = (unsigned short)bf16_rne(acc[12 + i][r]);
        unsigned ad16 = (unsigned short)bf16_rne(acc[i][r]);
        uint2 v;
        v.x = e16 | (as16 << 16);
        v.y = ts16 | (ad16 << 16);
        NPs4[(size_t)nd * 64 + i * 16 + row] = v;
        Ptd[(size_t)nd * 64 + i * 16 + row] = acc[16 + i][r];
      }
    }
}

// ---------------------------------------------------------------------------
// edge_pass_mfma: round-9 structure (dst-sorted edges, slot-cached dst rows,
// prefetched src gathers) at 8 WAVES/BLOCK. sWT (24KB) amortizes across 8
// waves -> LDS/block = 50.2KB -> 3 blocks/CU = 24 waves/CU (was 16). VGPR
// held <=85 via __launch_bounds__(512,6) so occupancy is LDS-limited only.
// Purpose: more outstanding scattered requests (e_feat random reads, out_e
// random writes, NPs4 gathers) -- rounds 5/8/9/10 all pinned at ~2.5 TB/s
// effective while round 3 showed 3.5 TB/s at higher occupancy.
// ---------------------------------------------------------------------------
__global__ __launch_bounds__(512, 6) void edge_pass_mfma(
    const float* __restrict__ e_feat, const int2* __restrict__ se,
    const int* __restrict__ sdst,
    const float* __restrict__ W_a, const float* __restrict__ W_T,
    const float* __restrict__ W_ee, const float* __restrict__ prelu_a,
    const uint2* __restrict__ NPs4,
    float* __restrict__ denom, float* __restrict__ numer,
    float* __restrict__ out_e) {
  __shared__ short sWT[192 * 64];      // 24 KB, W^T [C][k] bf16, XOR-swizzled
  __shared__ float sAcc[8][4 * 200];   // 25.6 KB per-wave transpose strips
  const int tid = threadIdx.x;
  const int lane = tid & 63;
  const int wid = tid >> 6;

  for (int idx = tid; idx < 192 * 32; idx += 512) {
    int C = idx >> 5;
    int k = (idx & 31) * 2;
    float f0, f1;
    if (C < 64)       { f0 = W_a[(128 + k) * 64 + C];        f1 = W_a[(129 + k) * 64 + C]; }
    else if (C < 128) { f0 = W_T[(128 + k) * 64 + (C - 64)]; f1 = W_T[(129 + k) * 64 + (C - 64)]; }
    else              { f0 = W_ee[k * 64 + (C - 128)];       f1 = W_ee[(k + 1) * 64 + (C - 128)]; }
    unsigned pack = ((unsigned)(unsigned short)bf16_rne(f0)) |
                    (((unsigned)(unsigned short)bf16_rne(f1)) << 16);
    int sidx = C * 64 + (((k >> 3) ^ (C & 7)) << 3) + (k & 7);
    *(unsigned*)(&sWT[sidx]) = pack;
  }
  __syncthreads();
  const float pa = prelu_a[0];

  const int row = lane & 15;
  const int q   = lane >> 4;
  float* sA = sAcc[wid];

  const int ngroups = N_EDGES / 128;   // 128 edges per block (16 per wave)
  for (int g = blockIdx.x; g < ngroups; g += gridDim.x) {
    const int ebase = g * 128 + wid * 16;

    // Edge meta: 2 vector loads (lanes replicate the 16 slots).
    const int2 se2 = se[ebase + row];
    const int dv = sdst[ebase + row];
    const int sv = se2.x;
    const int pv = se2.y;

    // e_feat loads FIRST (afrag convert can begin while ps flies).
    const float* pbase = e_feat + (size_t)pv * 64;
    float4 v00 = *(const float4*)(pbase + q * 8);
    float4 v01 = *(const float4*)(pbase + q * 8 + 4);
    float4 v10 = *(const float4*)(pbase + 32 + q * 8);
    float4 v11 = *(const float4*)(pbase + 32 + q * 8 + 4);

    // Prefetch src-endpoint gathers (static-indexed register array).
    uint2 ps[16];
    #pragma unroll
    for (int m = 0; m < 16; ++m) {
      int s_m = __builtin_amdgcn_readlane(sv, m);
      ps[m] = NPs4[(size_t)s_m * 64 + lane];
    }

    short8 afrag[2];
    {
      short8 a;
      a[0] = bf16_rne(v00.x); a[1] = bf16_rne(v00.y);
      a[2] = bf16_rne(v00.z); a[3] = bf16_rne(v00.w);
      a[4] = bf16_rne(v01.x); a[5] = bf16_rne(v01.y);
      a[6] = bf16_rne(v01.z); a[7] = bf16_rne(v01.w);
      afrag[0] = a;
      a[0] = bf16_rne(v10.x); a[1] = bf16_rne(v10.y);
      a[2] = bf16_rne(v10.z); a[3] = bf16_rne(v10.w);
      a[4] = bf16_rne(v11.x); a[5] = bf16_rne(v11.y);
      a[6] = bf16_rne(v11.z); a[7] = bf16_rne(v11.w);
      afrag[1] = a;
    }

    // MFMA (covers ps-gather latency): aa/at/ae[ct].
    f32x4 aa[4], at[4], ae[4];
    #pragma unroll
    for (int ct = 0; ct < 4; ++ct) {
      aa[ct] = (f32x4){0.f, 0.f, 0.f, 0.f};
      at[ct] = (f32x4){0.f, 0.f, 0.f, 0.f};
      ae[ct] = (f32x4){0.f, 0.f, 0.f, 0.f};
    }
    #pragma unroll
    for (int kt = 0; kt < 2; ++kt)
      #pragma unroll
      for (int ct = 0; ct < 4; ++ct) {
        int c = ct * 16 + row;
        int kg = ((kt * 4 + q) ^ (c & 7)) << 3;
        short8 ba = *(const short8*)(&sWT[(c)       * 64 + kg]);
        short8 bt = *(const short8*)(&sWT[(64 + c)  * 64 + kg]);
        short8 be = *(const short8*)(&sWT[(128 + c) * 64 + kg]);
        aa[ct] = __builtin_amdgcn_mfma_f32_16x16x32_bf16(afrag[kt], ba, aa[ct], 0, 0, 0);
        at[ct] = __builtin_amdgcn_mfma_f32_16x16x32_bf16(afrag[kt], bt, at[ct], 0, 0, 0);
        ae[ct] = __builtin_amdgcn_mfma_f32_16x16x32_bf16(afrag[kt], be, ae[ct], 0, 0, 0);
      }

    // Epilogue: 2-slot run-collapse with cached {e_d, ad_d} per slot.
    int dA = -1, dB = -1;
    float dsA = 0.f, nsA = 0.f, eA = 0.f, adA = 0.f;
    float dsB = 0.f, nsB = 0.f, eB = 0.f, adB = 0.f;

    #pragma unroll
    for (int r = 0; r < 4; ++r) {
      #pragma unroll
      for (int ct = 0; ct < 4; ++ct) {
        sA[q * 200 +       ct * 16 + row] = aa[ct][r];
        sA[q * 200 +  64 + ct * 16 + row] = at[ct][r];
        sA[q * 200 + 128 + ct * 16 + row] = ae[ct][r];
      }
      #pragma unroll
      for (int j = 0; j < 4; ++j) {
        const int m = j * 4 + r;  // edge index within wave tile
        int d  = __builtin_amdgcn_readlane(dv, m);
        int eo = __builtin_amdgcn_readlane(pv, m);
        float e_s  = __uint_as_float(ps[m].x << 16);
        float as_s = __uint_as_float(ps[m].x & 0xFFFF0000u);
        float ts_s = __uint_as_float(ps[m].y << 16);
        float aaE = sA[j * 200 + lane];
        float atE = sA[j * 200 + 64 + lane];
        float aeE = sA[j * 200 + 128 + lane];

        float e_d, ad_d;
        bool inA;
        if (d == dA) { e_d = eA; ad_d = adA; inA = true; }
        else if (d == dB) { e_d = eB; ad_d = adB; inA = false; }
        else {
          uint2 pdv = NPs4[(size_t)d * 64 + lane];   // wave-uniform d: one 512B gather
          e_d  = __uint_as_float(pdv.x << 16);
          ad_d = __uint_as_float(pdv.y & 0xFFFF0000u);
          if (dA < 0) { dA = d; dsA = 0.f; nsA = 0.f; eA = e_d; adA = ad_d; inA = true; }
          else {
            if (dB >= 0) {  // evict B
              atomicAdd(denom + (size_t)dB * 64 + lane, dsB);
              atomicAdd(numer + (size_t)dB * 64 + lane, nsB);
            }
            dB = d; dsB = 0.f; nsB = 0.f; eB = e_d; adB = ad_d; inA = false;
          }
        }

        float la = ad_d + aaE + as_s;
        float lg = la >= 0.f ? la : pa * la;
        float ex = __expf(lg);
        float exun = ex * (atE + ts_s);   // P_td hoisted to node_final
        out_e[(size_t)eo * 64 + lane] = e_s + e_d + aeE;

        if (inA) { dsA += ex; nsA += exun; }
        else     { dsB += ex; nsB += exun; }
      }
    }
    if (dA >= 0) {
      atomicAdd(denom + (size_t)dA * 64 + lane, dsA);
      atomicAdd(numer + (size_t)dA * 64 + lane, nsA);
    }
    if (dB >= 0) {
      atomicAdd(denom + (size_t)dB * 64 + lane, dsB);
      atomicAdd(numer + (size_t)dB * 64 + lane, nsB);
    }
  }
}

// node_final: out_n = denom>0 ? num/denom + P_td + b_T : 0.
__global__ __launch_bounds__(256) void node_final(
    const float* __restrict__ denom, const float* __restrict__ numer,
    const float* __restrict__ Ptd, const float* __restrict__ b_T,
    float* __restrict__ out_n) {
  int t = blockIdx.x * 256 + threadIdx.x;
  if (t >= N_NODES * 64) return;
  float dn = denom[t];
  out_n[t] = dn > 0.f ? numer[t] / dn + Ptd[t] + b_T[t & 63] : 0.f;
}

extern "C" void kernel_launch(void* const* d_in, const int* in_sizes, int n_in,
                              void* d_out, int out_size, void* d_ws, size_t ws_size,
                              hipStream_t stream) {
  const float* n_feat  = (const float*)d_in[0];
  const float* e_feat  = (const float*)d_in[1];
  const int*   src     = (const int*)d_in[2];
  const int*   dst     = (const int*)d_in[3];
  const float* W_a     = (const float*)d_in[4];
  const float* W_T     = (const float*)d_in[5];
  const float* b_T     = (const float*)d_in[6];
  const float* W_e     = (const float*)d_in[7];
  const float* W_ee    = (const float*)d_in[8];
  const float* prelu_a = (const float*)d_in[9];

  float* out_n = (float*)d_out;
  float* out_e = out_n + (size_t)N_NODES * 64;

  // ws layout (~75 MB)
  uint2* NPs4  = (uint2*)d_ws;                                        // 25.6 MB
  float* Ptd   = (float*)((char*)d_ws + (size_t)N_NODES * 64 * 8);    // 12.8 MB
  float* denom = Ptd + (size_t)N_NODES * 64;                          // 12.8 MB
  float* numer = denom + (size_t)N_NODES * 64;                        // 12.8 MB
  unsigned short* Wbf = (unsigned short*)(numer + (size_t)N_NODES * 64);  // 80 KB
  unsigned* hist   = (unsigned*)(Wbf + 40960);                        // 200 KB
  unsigned* cursor = hist + N_NODES;                                  // 200 KB
  int2* se = (int2*)(cursor + N_NODES);                               // 6.4 MB
  int* sdst = (int*)(se + N_EDGES);                                   // 3.2 MB

  hipMemsetAsync(denom, 0, (size_t)N_NODES * 64 * 2 * sizeof(float), stream);
  hipMemsetAsync(hist, 0, (size_t)N_NODES * sizeof(unsigned), stream);

  hist_prep<<<N_EDGES / 256 + 160, 256, 0, stream>>>(dst, hist, W_a, W_T, W_e, Wbf);
  scan_cursor<<<1, 1024, 0, stream>>>(hist, cursor);
  scatter_kernel<<<(N_EDGES + 255) / 256, 256, 0, stream>>>(src, dst, cursor, se, sdst);
  node_proj_mfma<<<(N_NODES + 63) / 64, 256, 0, stream>>>(n_feat, Wbf, NPs4, Ptd);
  edge_pass_mfma<<<2048, 512, 0, stream>>>(e_feat, se, sdst, W_a, W_T, W_ee,
                                           prelu_a, NPs4, denom, numer, out_e);
  node_final<<<(N_NODES * 64 + 255) / 256, 256, 0, stream>>>(denom, numer, Ptd, b_T, out_n);
}

// Round 12
// 406.732 us; speedup vs baseline: 2.0077x; 2.0077x over previous
//
#include <hip/hip_runtime.h>

#define N_NODES 50000
#define N_EDGES 800000

typedef __attribute__((ext_vector_type(8))) short short8;
typedef __attribute__((ext_vector_type(4))) float f32x4;

// float -> bf16 (round-to-nearest-even), bit pattern in a short.
__device__ __forceinline__ short bf16_rne(float f) {
  unsigned u = __float_as_uint(f);
  unsigned r = (u + 0x7FFFu + ((u >> 16) & 1u)) >> 16;
  return (short)r;
}

// ---------------------------------------------------------------------------
// hist_prep: fused dst-histogram + frag-linear bf16 weight table build.
// ---------------------------------------------------------------------------
__global__ __launch_bounds__(256) void hist_prep(
    const int* __restrict__ dst, unsigned* __restrict__ hist,
    const float* __restrict__ W_a, const float* __restrict__ W_T,
    const float* __restrict__ W_e, unsigned short* __restrict__ Wbf) {
  const int bid = blockIdx.x;
  if (bid < N_EDGES / 256) {
    int e = bid * 256 + threadIdx.x;
    atomicAdd(&hist[dst[e]], 1u);
  } else {
    int t = (bid - N_EDGES / 256) * 256 + threadIdx.x;
    if (t >= 4 * 20 * 64 * 8) return;
    int kt = t / 10240, rdm = t % 10240;
    int ct = rdm >> 9, L = (rdm >> 3) & 63, j = rdm & 7;
    int k = kt * 32 + (L >> 4) * 8 + j;
    int oc = ct * 16 + (L & 15);
    float v;
    if (oc < 64)       v = W_a[k * 64 + oc];
    else if (oc < 128) v = W_e[k * 64 + (oc - 64)];
    else if (oc < 192) v = W_a[(192 + k) * 64 + (oc - 128)];
    else if (oc < 256) v = W_T[(192 + k) * 64 + (oc - 192)];
    else               v = W_T[k * 64 + (oc - 256)];
    Wbf[t] = (unsigned short)bf16_rne(v);
  }
}

// ---------------------------------------------------------------------------
// scan_cursor: one block, 1024 threads, 2-level exclusive scan of hist.
// ---------------------------------------------------------------------------
__global__ __launch_bounds__(1024) void scan_cursor(
    const unsigned* __restrict__ hist, unsigned* __restrict__ cursor) {
  __shared__ unsigned sSums[16];
  const int tid = threadIdx.x;
  const int lane = tid & 63;
  const int w = tid >> 6;
  const int CH = (N_NODES + 1023) / 1024;  // 49
  const int begin = tid * CH;
  const int end = (begin + CH < N_NODES) ? begin + CH : N_NODES;

  unsigned local = 0;
  for (int i = begin; i < end; ++i) local += hist[i];

  unsigned sum = local;
  #pragma unroll
  for (int off = 1; off < 64; off <<= 1) {
    unsigned t = __shfl_up(sum, off, 64);
    if (lane >= off) sum += t;
  }
  if (lane == 63) sSums[w] = sum;
  __syncthreads();
  if (w == 0) {
    unsigned v = (lane < 16) ? sSums[lane] : 0u;
    unsigned s2 = v;
    #pragma unroll
    for (int off = 1; off < 16; off <<= 1) {
      unsigned t = __shfl_up(s2, off, 64);
      if (lane >= off) s2 += t;
    }
    if (lane < 16) sSums[lane] = s2 - v;
  }
  __syncthreads();

  unsigned run = sSums[w] + (sum - local);
  for (int i = begin; i < end; ++i) {
    cursor[i] = run;
    run += hist[i];
  }
}

// ---------------------------------------------------------------------------
// scatter: edge e -> dst-sorted slot; payload int2{src, e} + sdst.
// ---------------------------------------------------------------------------
__global__ __launch_bounds__(256) void scatter_kernel(
    const int* __restrict__ src, const int* __restrict__ dst,
    unsigned* __restrict__ cursor, int2* __restrict__ se,
    int* __restrict__ sdst) {
  int e = blockIdx.x * 256 + threadIdx.x;
  if (e >= N_EDGES) return;
  int d = dst[e];
  unsigned pos = atomicAdd(&cursor[d], 1u);
  se[pos] = make_int2(src[e], e);
  sdst[pos] = d;
}

// ---------------------------------------------------------------------------
// node_proj_mfma: NP = n_feat @ [Wa_d|W_e|Wa_s|Wt_s|Wt_d] via bf16 MFMA.
// Also zeroes this block's denom/numer slice (replaces the 25.6MB memset).
// Packed gather table: NPs4[n][lane] = uint2{ e | as<<16 , ts | ad<<16 }.
// ---------------------------------------------------------------------------
__global__ __launch_bounds__(256) void node_proj_mfma(
    const float* __restrict__ n_feat, const unsigned short* __restrict__ Wbf,
    uint2* __restrict__ NPs4, float* __restrict__ Ptd,
    float4* __restrict__ denom4, float4* __restrict__ numer4) {
  __shared__ short sA[64 * 128];  // 16 KB bf16
  const int tid = threadIdx.x;
  const int lane = tid & 63;
  const int wid = tid >> 6;
  const int n0 = blockIdx.x * 64;

  // Zero denom/numer slice for nodes [n0, n0+64): 1024 float4 per buffer.
  {
    const float4 z = make_float4(0.f, 0.f, 0.f, 0.f);
    size_t base = (size_t)n0 * 16;  // 64 floats/node = 16 float4/node
    size_t lim = (size_t)N_NODES * 16;
    #pragma unroll
    for (int i = 0; i < 4; ++i) {
      size_t idx = base + i * 256 + tid;
      if (idx < lim) { denom4[idx] = z; numer4[idx] = z; }
    }
  }

  for (int cid = tid; cid < 64 * 16; cid += 256) {
    int nd = cid >> 4, k8 = cid & 15;
    int nsrc = n0 + nd; if (nsrc >= N_NODES) nsrc = N_NODES - 1;
    const float* p = n_feat + (size_t)nsrc * 128 + k8 * 8;
    float4 v0 = *(const float4*)p;
    float4 v1 = *(const float4*)(p + 4);
    short8 a;
    a[0] = bf16_rne(v0.x); a[1] = bf16_rne(v0.y);
    a[2] = bf16_rne(v0.z); a[3] = bf16_rne(v0.w);
    a[4] = bf16_rne(v1.x); a[5] = bf16_rne(v1.y);
    a[6] = bf16_rne(v1.z); a[7] = bf16_rne(v1.w);
    *(short8*)(&sA[nd * 128 + ((k8 ^ (nd & 7)) << 3)]) = a;
  }
  __syncthreads();

  const int row = lane & 15;
  const int q   = lane >> 4;

  short8 afrag[4];
  #pragma unroll
  for (int kt = 0; kt < 4; ++kt) {
    int nd = wid * 16 + row;
    afrag[kt] = *(const short8*)(&sA[nd * 128 + (((kt * 4 + q) ^ (row & 7)) << 3)]);
  }

  const short8* Wb8 = (const short8*)Wbf;
  f32x4 acc[20];
  #pragma unroll
  for (int ct = 0; ct < 20; ++ct) acc[ct] = (f32x4){0.f, 0.f, 0.f, 0.f};
  #pragma unroll
  for (int ct = 0; ct < 20; ++ct)
    #pragma unroll
    for (int kt = 0; kt < 4; ++kt) {
      short8 b = Wb8[(kt * 20 + ct) * 64 + lane];
      acc[ct] = __builtin_amdgcn_mfma_f32_16x16x32_bf16(afrag[kt], b, acc[ct], 0, 0, 0);
    }

  // D layout: col = i*16 + row, node-row = q*4 + r  [m89-verified]
  #pragma unroll
  for (int i = 0; i < 4; ++i)
    #pragma unroll
    for (int r = 0; r < 4; ++r) {
      int nd = n0 + wid * 16 + q * 4 + r;
      if (nd < N_NODES) {
        unsigned e16  = (unsigned short)bf16_rne(acc[4  + i][r]);
        unsigned as16 = (unsigned short)bf16_rne(acc[8  + i][r]);
        unsigned ts16 = (unsigned short)bf16_rne(acc[12 + i][r]);
        unsigned ad16 = (unsigned short)bf16_rne(acc[i][r]);
        uint2 v;
        v.x = e16 | (as16 << 16);
        v.y = ts16 | (ad16 << 16);
        NPs4[(size_t)nd * 64 + i * 16 + row] = v;
        Ptd[(size_t)nd * 64 + i * 16 + row] = acc[16 + i][r];
      }
    }
}

// ---------------------------------------------------------------------------
// edge_pass_mfma: round-9 algorithm at 8 waves/block.
// launch_bounds(512, 2): VGPR cap 256 -> NO spill (round 11's (512,6) capped
// at 85 while the kernel needs ~80 VGPR + 48 acc regs in the unified file ->
// everything spilled, 1.7GB scratch traffic). LDS 50.2KB -> 3 blocks/CU =
// 24 waves/CU (round 9: 16). Round 11 proved the memory system gives
// 3.3 TB/s at this concurrency -- this reruns it without the spill.
// ---------------------------------------------------------------------------
__global__ __launch_bounds__(512, 2) void edge_pass_mfma(
    const float* __restrict__ e_feat, const int2* __restrict__ se,
    const int* __restrict__ sdst,
    const float* __restrict__ W_a, const float* __restrict__ W_T,
    const float* __restrict__ W_ee, const float* __restrict__ prelu_a,
    const uint2* __restrict__ NPs4,
    float* __restrict__ denom, float* __restrict__ numer,
    float* __restrict__ out_e) {
  __shared__ short sWT[192 * 64];      // 24 KB, W^T [C][k] bf16, XOR-swizzled
  __shared__ float sAcc[8][4 * 200];   // 25.6 KB per-wave transpose strips
  const int tid = threadIdx.x;
  const int lane = tid & 63;
  const int wid = tid >> 6;

  for (int idx = tid; idx < 192 * 32; idx += 512) {
    int C = idx >> 5;
    int k = (idx & 31) * 2;
    float f0, f1;
    if (C < 64)       { f0 = W_a[(128 + k) * 64 + C];        f1 = W_a[(129 + k) * 64 + C]; }
    else if (C < 128) { f0 = W_T[(128 + k) * 64 + (C - 64)]; f1 = W_T[(129 + k) * 64 + (C - 64)]; }
    else              { f0 = W_ee[k * 64 + (C - 128)];       f1 = W_ee[(k + 1) * 64 + (C - 128)]; }
    unsigned pack = ((unsigned)(unsigned short)bf16_rne(f0)) |
                    (((unsigned)(unsigned short)bf16_rne(f1)) << 16);
    int sidx = C * 64 + (((k >> 3) ^ (C & 7)) << 3) + (k & 7);
    *(unsigned*)(&sWT[sidx]) = pack;
  }
  __syncthreads();
  const float pa = prelu_a[0];

  const int row = lane & 15;
  const int q   = lane >> 4;
  float* sA = sAcc[wid];

  const int ngroups = N_EDGES / 128;   // 128 edges per block (16 per wave)
  for (int g = blockIdx.x; g < ngroups; g += gridDim.x) {
    const int ebase = g * 128 + wid * 16;

    // Edge meta: 2 vector loads (lanes replicate the 16 slots).
    const int2 se2 = se[ebase + row];
    const int dv = sdst[ebase + row];
    const int sv = se2.x;
    const int pv = se2.y;

    // e_feat loads FIRST (afrag convert can begin while ps flies).
    const float* pbase = e_feat + (size_t)pv * 64;
    float4 v00 = *(const float4*)(pbase + q * 8);
    float4 v01 = *(const float4*)(pbase + q * 8 + 4);
    float4 v10 = *(const float4*)(pbase + 32 + q * 8);
    float4 v11 = *(const float4*)(pbase + 32 + q * 8 + 4);

    // Prefetch src-endpoint gathers (static-indexed register array).
    uint2 ps[16];
    #pragma unroll
    for (int m = 0; m < 16; ++m) {
      int s_m = __builtin_amdgcn_readlane(sv, m);
      ps[m] = NPs4[(size_t)s_m * 64 + lane];
    }

    short8 afrag[2];
    {
      short8 a;
      a[0] = bf16_rne(v00.x); a[1] = bf16_rne(v00.y);
      a[2] = bf16_rne(v00.z); a[3] = bf16_rne(v00.w);
      a[4] = bf16_rne(v01.x); a[5] = bf16_rne(v01.y);
      a[6] = bf16_rne(v01.z); a[7] = bf16_rne(v01.w);
      afrag[0] = a;
      a[0] = bf16_rne(v10.x); a[1] = bf16_rne(v10.y);
      a[2] = bf16_rne(v10.z); a[3] = bf16_rne(v10.w);
      a[4] = bf16_rne(v11.x); a[5] = bf16_rne(v11.y);
      a[6] = bf16_rne(v11.z); a[7] = bf16_rne(v11.w);
      afrag[1] = a;
    }

    // MFMA (covers ps-gather latency): aa/at/ae[ct].
    f32x4 aa[4], at[4], ae[4];
    #pragma unroll
    for (int ct = 0; ct < 4; ++ct) {
      aa[ct] = (f32x4){0.f, 0.f, 0.f, 0.f};
      at[ct] = (f32x4){0.f, 0.f, 0.f, 0.f};
      ae[ct] = (f32x4){0.f, 0.f, 0.f, 0.f};
    }
    #pragma unroll
    for (int kt = 0; kt < 2; ++kt)
      #pragma unroll
      for (int ct = 0; ct < 4; ++ct) {
        int c = ct * 16 + row;
        int kg = ((kt * 4 + q) ^ (c & 7)) << 3;
        short8 ba = *(const short8*)(&sWT[(c)       * 64 + kg]);
        short8 bt = *(const short8*)(&sWT[(64 + c)  * 64 + kg]);
        short8 be = *(const short8*)(&sWT[(128 + c) * 64 + kg]);
        aa[ct] = __builtin_amdgcn_mfma_f32_16x16x32_bf16(afrag[kt], ba, aa[ct], 0, 0, 0);
        at[ct] = __builtin_amdgcn_mfma_f32_16x16x32_bf16(afrag[kt], bt, at[ct], 0, 0, 0);
        ae[ct] = __builtin_amdgcn_mfma_f32_16x16x32_bf16(afrag[kt], be, ae[ct], 0, 0, 0);
      }

    // Epilogue: 2-slot run-collapse with cached {e_d, ad_d} per slot.
    int dA = -1, dB = -1;
    float dsA = 0.f, nsA = 0.f, eA = 0.f, adA = 0.f;
    float dsB = 0.f, nsB = 0.f, eB = 0.f, adB = 0.f;

    #pragma unroll
    for (int r = 0; r < 4; ++r) {
      #pragma unroll
      for (int ct = 0; ct < 4; ++ct) {
        sA[q * 200 +       ct * 16 + row] = aa[ct][r];
        sA[q * 200 +  64 + ct * 16 + row] = at[ct][r];
        sA[q * 200 + 128 + ct * 16 + row] = ae[ct][r];
      }
      #pragma unroll
      for (int j = 0; j < 4; ++j) {
        const int m = j * 4 + r;  // edge index within wave tile
        int d  = __builtin_amdgcn_readlane(dv, m);
        int eo = __builtin_amdgcn_readlane(pv, m);
        float e_s  = __uint_as_float(ps[m].x << 16);
        float as_s = __uint_as_float(ps[m].x & 0xFFFF0000u);
        float ts_s = __uint_as_float(ps[m].y << 16);
        float aaE = sA[j * 200 + lane];
        float atE = sA[j * 200 + 64 + lane];
        float aeE = sA[j * 200 + 128 + lane];

        float e_d, ad_d;
        bool inA;
        if (d == dA) { e_d = eA; ad_d = adA; inA = true; }
        else if (d == dB) { e_d = eB; ad_d = adB; inA = false; }
        else {
          uint2 pdv = NPs4[(size_t)d * 64 + lane];   // wave-uniform d: one 512B gather
          e_d  = __uint_as_float(pdv.x << 16);
          ad_d = __uint_as_float(pdv.y & 0xFFFF0000u);
          if (dA < 0) { dA = d; dsA = 0.f; nsA = 0.f; eA = e_d; adA = ad_d; inA = true; }
          else {
            if (dB >= 0) {  // evict B
              atomicAdd(denom + (size_t)dB * 64 + lane, dsB);
              atomicAdd(numer + (size_t)dB * 64 + lane, nsB);
            }
            dB = d; dsB = 0.f; nsB = 0.f; eB = e_d; adB = ad_d; inA = false;
          }
        }

        float la = ad_d + aaE + as_s;
        float lg = la >= 0.f ? la : pa * la;
        float ex = __expf(lg);
        float exun = ex * (atE + ts_s);   // P_td hoisted to node_final
        out_e[(size_t)eo * 64 + lane] = e_s + e_d + aeE;

        if (inA) { dsA += ex; nsA += exun; }
        else     { dsB += ex; nsB += exun; }
      }
    }
    if (dA >= 0) {
      atomicAdd(denom + (size_t)dA * 64 + lane, dsA);
      atomicAdd(numer + (size_t)dA * 64 + lane, nsA);
    }
    if (dB >= 0) {
      atomicAdd(denom + (size_t)dB * 64 + lane, dsB);
      atomicAdd(numer + (size_t)dB * 64 + lane, nsB);
    }
  }
}

// node_final: out_n = denom>0 ? num/denom + P_td + b_T : 0.
__global__ __launch_bounds__(256) void node_final(
    const float* __restrict__ denom, const float* __restrict__ numer,
    const float* __restrict__ Ptd, const float* __restrict__ b_T,
    float* __restrict__ out_n) {
  int t = blockIdx.x * 256 + threadIdx.x;
  if (t >= N_NODES * 64) return;
  float dn = denom[t];
  out_n[t] = dn > 0.f ? numer[t] / dn + Ptd[t] + b_T[t & 63] : 0.f;
}

extern "C" void kernel_launch(void* const* d_in, const int* in_sizes, int n_in,
                              void* d_out, int out_size, void* d_ws, size_t ws_size,
                              hipStream_t stream) {
  const float* n_feat  = (const float*)d_in[0];
  const float* e_feat  = (const float*)d_in[1];
  const int*   src     = (const int*)d_in[2];
  const int*   dst     = (const int*)d_in[3];
  const float* W_a     = (const float*)d_in[4];
  const float* W_T     = (const float*)d_in[5];
  const float* b_T     = (const float*)d_in[6];
  const float* W_e     = (const float*)d_in[7];
  const float* W_ee    = (const float*)d_in[8];
  const float* prelu_a = (const float*)d_in[9];

  float* out_n = (float*)d_out;
  float* out_e = out_n + (size_t)N_NODES * 64;

  // ws layout (~75 MB)
  uint2* NPs4  = (uint2*)d_ws;                                        // 25.6 MB
  float* Ptd   = (float*)((char*)d_ws + (size_t)N_NODES * 64 * 8);    // 12.8 MB
  float* denom = Ptd + (size_t)N_NODES * 64;                          // 12.8 MB
  float* numer = denom + (size_t)N_NODES * 64;                        // 12.8 MB
  unsigned short* Wbf = (unsigned short*)(numer + (size_t)N_NODES * 64);  // 80 KB
  unsigned* hist   = (unsigned*)(Wbf + 40960);                        // 200 KB
  unsigned* cursor = hist + N_NODES;                                  // 200 KB
  int2* se = (int2*)(cursor + N_NODES);                               // 6.4 MB
  int* sdst = (int*)(se + N_EDGES);                                   // 3.2 MB

  hipMemsetAsync(hist, 0, (size_t)N_NODES * sizeof(unsigned), stream);
  hist_prep<<<N_EDGES / 256 + 160, 256, 0, stream>>>(dst, hist, W_a, W_T, W_e, Wbf);
  scan_cursor<<<1, 1024, 0, stream>>>(hist, cursor);
  scatter_kernel<<<(N_EDGES + 255) / 256, 256, 0, stream>>>(src, dst, cursor, se, sdst);
  node_proj_mfma<<<(N_NODES + 63) / 64, 256, 0, stream>>>(
      n_feat, Wbf, NPs4, Ptd, (float4*)denom, (float4*)numer);
  edge_pass_mfma<<<2048, 512, 0, stream>>>(e_feat, se, sdst, W_a, W_T, W_ee,
                                           prelu_a, NPs4, denom, numer, out_e);
  node_final<<<(N_NODES * 64 + 255) / 256, 256, 0, stream>>>(denom, numer, Ptd, b_T, out_n);
}